// Round 5
// baseline (1436.553 us; speedup 1.0000x reference)
//
#include <hip/hip_runtime.h>
#include <math.h>

#define HW 512
#define MASK 511
#define IMG (512*512)
#define NSTEP 16
#define NSLICE 17

#define IN_Y 84            // staged rows  [Y0-10, Y0+74)
#define IN_XP 92           // LDS row stride (odd granule count -> conflict-free)
#define IN_XQ 22           // staged quads/row (88 floats: gcols [X0-12, X0+76))
#define BAR_OFF 1024       // int offset of barrier state in ws

__global__ void prep_kernel(const float* __restrict__ w1,
                            const float* __restrict__ w2,
                            const float* __restrict__ w3,
                            float* __restrict__ ws) {
    int i = threadIdx.x;
    for (int idx = i; idx < 21 * 24; idx += blockDim.x) {
        int r = idx / 24, c = idx - r * 24;
        ws[idx] = (c < 21) ? w1[r * 21 + c] : 0.f;   // pad cols 21..23 = 0
    }
    if (i == 0) {
        // 1->10->1 MLP on nonneg scalar collapses: C = sum_o w3[o]*max(w2[o],0)
        float c = 0.f;
        for (int o = 0; o < 10; ++o) c += w3[o] * fmaxf(w2[o], 0.f);
        ws[504] = c;
    }
    // zero grid-barrier state EVERY launch (ws poisoned once, replays reuse)
    int* bar = (int*)ws + BAR_OFF;
    for (int idx = i; idx < 576; idx += blockDim.x) bar[idx] = 0;
}

__global__ void copy_kernel(const float* __restrict__ x, float* __restrict__ out) {
    int i = blockIdx.x * blockDim.x + threadIdx.x;   // float4 index
    if (i < 8 * 65536) {
        const float4* in4 = (const float4*)x;
        float4* out4 = (float4*)out;
        int b = i >> 16;
        int off = i & 65535;
        out4[(size_t)b * (NSLICE * 65536) + off] = in4[i];
    }
}

// hierarchical grid barrier: 16 groups x 32 blocks, 128B-spaced counters.
// gen = step t (monotone within launch; prep resets flag each launch).
__device__ __forceinline__ void grid_sync(int* bar, int gen, int bid) {
    __syncthreads();
    if (threadIdx.x == 0 && threadIdx.y == 0) {
        __threadfence();                               // flush my global writes
        int* gcnt = bar + (bid & 15) * 32;
        int* mcnt = bar + 512;
        int* flag = bar + 544;
        if (__hip_atomic_fetch_add(gcnt, 1, __ATOMIC_ACQ_REL,
                                   __HIP_MEMORY_SCOPE_AGENT) == 31) {
            __hip_atomic_store(gcnt, 0, __ATOMIC_RELAXED, __HIP_MEMORY_SCOPE_AGENT);
            if (__hip_atomic_fetch_add(mcnt, 1, __ATOMIC_ACQ_REL,
                                       __HIP_MEMORY_SCOPE_AGENT) == 15) {
                __hip_atomic_store(mcnt, 0, __ATOMIC_RELAXED, __HIP_MEMORY_SCOPE_AGENT);
                __hip_atomic_store(flag, gen, __ATOMIC_RELEASE, __HIP_MEMORY_SCOPE_AGENT);
            }
        }
        while (__hip_atomic_load(flag, __ATOMIC_ACQUIRE,
                                 __HIP_MEMORY_SCOPE_AGENT) < gen)
            __builtin_amdgcn_s_sleep(2);
        __threadfence();                               // invalidate stale lines
    }
    __syncthreads();
}

__global__ __launch_bounds__(256, 2)
void nca_fused(const float* __restrict__ x, float* __restrict__ out,
               const float* __restrict__ wsf, int* __restrict__ bar) {
    __shared__ float tile[IN_Y * IN_XP];   // 30.2 KiB, persistent across steps
    __shared__ float wlds[512];            // padded weights

    const int tx = threadIdx.x, ty = threadIdx.y;
    const int tid = tx + (ty << 3);
    const int X0 = blockIdx.x * 64, Y0 = blockIdx.y * 64;
    const int b = blockIdx.z;
    const int bid = blockIdx.x + (blockIdx.y << 3) + (blockIdx.z << 6);

    for (int j = tid; j < 126; j += 256)
        *(float4*)&wlds[4 * j] = *(const float4*)&wsf[4 * j];
    const float C = wsf[504];

    // initial stage: full 84x88 window of input image b
    const float* im0 = x + (size_t)b * IMG;
    for (int j = tid; j < IN_Y * IN_XQ; j += 256) {
        int r = j / IN_XQ, k = j - r * IN_XQ;
        int gr = (Y0 + r - 10) & MASK;
        int gc = (X0 + 4 * k - 12) & MASK;
        *(float4*)&tile[r * IN_XP + 4 * k] = *(const float4*)&im0[gr * HW + gc];
    }
    __syncthreads();

    const int c0 = tx << 3;                // 8 cols/thread
    const int r0 = ty << 1;                // 2 rows/thread
    float* const wbase = &tile[r0 * IN_XP + c0];

    float win[32], wA[24], wB[24];

    auto LOADWIN = [&](int rr) {
        #pragma unroll
        for (int k = 0; k < 8; ++k) {
            float4 q = *(const float4*)&wbase[rr * IN_XP + 4 * k];
            win[4*k] = q.x; win[4*k+1] = q.y; win[4*k+2] = q.z; win[4*k+3] = q.w;
        }
    };
    auto LOADW = [&](float* w, int rr) {   // broadcast (same addr all lanes)
        #pragma unroll
        for (int k = 0; k < 6; ++k) {
            float4 q = *(const float4*)&wlds[rr * 24 + 4 * k];
            w[4*k] = q.x; w[4*k+1] = q.y; w[4*k+2] = q.z; w[4*k+3] = q.w;
        }
    };
    auto CONV = [&](float* acc, const float* w) {
        #pragma unroll
        for (int dx = 0; dx < 21; ++dx)
            #pragma unroll
            for (int cc = 0; cc < 8; ++cc)
                acc[cc] = fmaf(w[dx], win[cc + dx + 2], acc[cc]);
    };

    #pragma unroll 1
    for (int t = 1; t <= NSTEP; ++t) {
        float* slice = out + (size_t)(b * NSLICE + t) * IMG;

        float acc0[8], acc1[8];
        #pragma unroll
        for (int cc = 0; cc < 8; ++cc) { acc0[cc] = 0.f; acc1[cc] = 0.f; }

        // staged row r0+rr feeds out0 with weight row rr, out1 with rr-1
        LOADW(wA, 0); LOADWIN(0); CONV(acc0, wA);
        LOADW(wB, 1); LOADWIN(1); CONV(acc0, wB); CONV(acc1, wA);
        #pragma unroll 1
        for (int i = 1; i <= 9; ++i) {     // invariant: wB = weight row 2i-1
            LOADW(wA, 2*i);   LOADWIN(2*i);   CONV(acc0, wA); CONV(acc1, wB);
            LOADW(wB, 2*i+1); LOADWIN(2*i+1); CONV(acc0, wB); CONV(acc1, wA);
        }
        LOADW(wA, 20); LOADWIN(20); CONV(acc0, wA); CONV(acc1, wB);
        LOADWIN(21); CONV(acc1, wA);

        // centers (residual x) re-read from LDS
        float4 u0 = *(const float4*)&wbase[10 * IN_XP + 12];
        float4 u1 = *(const float4*)&wbase[10 * IN_XP + 16];
        float4 v0 = *(const float4*)&wbase[11 * IN_XP + 12];
        float4 v1 = *(const float4*)&wbase[11 * IN_XP + 16];
        float ctr0[8] = {u0.x,u0.y,u0.z,u0.w,u1.x,u1.y,u1.z,u1.w};
        float ctr1[8] = {v0.x,v0.y,v0.z,v0.w,v1.x,v1.y,v1.z,v1.w};
        float o0[8], o1[8];
        #pragma unroll
        for (int cc = 0; cc < 8; ++cc) {
            float a  = ctr0[cc] + C * fmaxf(acc0[cc], 0.f);
            float e  = __expf(2.f * fabsf(a));
            float rr = 1.f - 2.f * __builtin_amdgcn_rcpf(e + 1.f);
            o0[cc]   = copysignf(rr, a);
            float a1 = ctr1[cc] + C * fmaxf(acc1[cc], 0.f);
            float e1 = __expf(2.f * fabsf(a1));
            float r1 = 1.f - 2.f * __builtin_amdgcn_rcpf(e1 + 1.f);
            o1[cc]   = copysignf(r1, a1);
        }

        __syncthreads();   // everyone done reading tile
        // update LDS interior + write global slice
        *(float4*)&wbase[10 * IN_XP + 12] = make_float4(o0[0], o0[1], o0[2], o0[3]);
        *(float4*)&wbase[10 * IN_XP + 16] = make_float4(o0[4], o0[5], o0[6], o0[7]);
        *(float4*)&wbase[11 * IN_XP + 12] = make_float4(o1[0], o1[1], o1[2], o1[3]);
        *(float4*)&wbase[11 * IN_XP + 16] = make_float4(o1[4], o1[5], o1[6], o1[7]);
        float4* po0 = (float4*)&slice[(size_t)(Y0 + r0) * HW + X0 + c0];
        po0[0] = make_float4(o0[0], o0[1], o0[2], o0[3]);
        po0[1] = make_float4(o0[4], o0[5], o0[6], o0[7]);
        float4* po1 = (float4*)&slice[(size_t)(Y0 + r0 + 1) * HW + X0 + c0];
        po1[0] = make_float4(o1[0], o1[1], o1[2], o1[3]);
        po1[1] = make_float4(o1[4], o1[5], o1[6], o1[7]);

        if (t < NSTEP) {
            grid_sync(bar, t, bid);
            // refresh halo ring (824 quads) from the slice just written.
            // interior cols are 12..75 -> left halo quads {0,4,8},
            // RIGHT halo quads {76,80,84}  (R4 bug: was 64/68/72 = interior)
            #pragma unroll 1
            for (int j = tid; j < 824; j += 256) {
                int r, c4;
                if (j < 440) {                       // top 10 + bottom 10 full rows
                    int rr2 = j / 22;
                    r  = (rr2 < 10) ? rr2 : rr2 + 64;
                    c4 = (j - rr2 * 22) * 4;
                } else {                             // side strips, rows 10..73
                    int s = j - 440;
                    int q = s / 6, k = s - q * 6;
                    r  = 10 + q;
                    c4 = (k < 3) ? 4 * k : 76 + 4 * (k - 3);
                }
                int gr = (Y0 + r - 10) & MASK;
                int gc = (X0 + c4 - 12) & MASK;
                *(float4*)&tile[r * IN_XP + c4] = *(const float4*)&slice[gr * HW + gc];
            }
            __syncthreads();
        }
    }
}

extern "C" void kernel_launch(void* const* d_in, const int* in_sizes, int n_in,
                              void* d_out, int out_size, void* d_ws, size_t ws_size,
                              hipStream_t stream) {
    const float* x  = (const float*)d_in[0];
    const float* w1 = (const float*)d_in[1];
    const float* w2 = (const float*)d_in[2];
    const float* w3 = (const float*)d_in[3];
    float* out = (float*)d_out;
    float* ws  = (float*)d_ws;
    int* bar   = (int*)ws + BAR_OFF;

    prep_kernel<<<1, 128, 0, stream>>>(w1, w2, w3, ws);
    copy_kernel<<<2048, 256, 0, stream>>>(x, out);

    dim3 grid(8, 8, 8);      // 512 blocks; >=2/CU guaranteed -> all co-resident
    dim3 block(8, 32);
    nca_fused<<<grid, block, 0, stream>>>(x, out, ws, bar);
}

// Round 6
// 440.985 us; speedup vs baseline: 3.2576x; 3.2576x over previous
//
#include <hip/hip_runtime.h>
#include <math.h>

#define HW 512
#define MASK 511
#define IMG (512*512)
#define NSTEP 16
#define NSLICE 17

#define IN_Y 84            // staged rows [Y0-10, Y0+74)
#define ROWW 96            // LDS words per row (24 granules)
#define NQ 22              // staged quads per row (88 floats: gcols [X0-12, X0+76))

// XOR-swizzled quad address: one ds_*_b128 = one 16B granule, so XOR at
// granule granularity keeps accesses aligned+contiguous. Mask (r>>1)&7 varies
// with ty (r = 2*ty + rr) -> 64 lanes cover all 8 granule classes uniformly.
__device__ __forceinline__ int lds_q(int r, int q) {
    return r * ROWW + ((q ^ ((r >> 1) & 7)) << 2);
}

__global__ void prep_kernel(const float* __restrict__ w1,
                            const float* __restrict__ w2,
                            const float* __restrict__ w3,
                            float* __restrict__ ws) {
    int i = threadIdx.x;
    for (int idx = i; idx < 21 * 24; idx += blockDim.x) {
        int r = idx / 24, c = idx - r * 24;
        ws[idx] = (c < 21) ? w1[r * 21 + c] : 0.f;   // rows padded to 24 floats
    }
    if (i == 0) {
        // 1->10->1 MLP on nonneg scalar collapses: C = sum_o w3[o]*max(w2[o],0)
        float c = 0.f;
        for (int o = 0; o < 10; ++o) c += w3[o] * fmaxf(w2[o], 0.f);
        ws[504] = c;
    }
    for (int idx = 505 + i; idx < 512; idx += blockDim.x) ws[idx] = 0.f;
}

__global__ void copy_kernel(const float* __restrict__ x, float* __restrict__ out) {
    int i = blockIdx.x * blockDim.x + threadIdx.x;   // float4 index
    if (i < 8 * 65536) {
        const float4* in4 = (const float4*)x;
        float4* out4 = (float4*)out;
        int b = i >> 16;
        int off = i & 65535;
        out4[(size_t)b * (NSLICE * 65536) + off] = in4[i];
    }
}

__global__ __launch_bounds__(256, 2)
void step_kernel(const float* __restrict__ state_base,
                 float* __restrict__ out_base,
                 const float* __restrict__ wsf,
                 int t) {
    __shared__ float tile[IN_Y * ROWW];   // 31.5 KiB
    __shared__ float wlds[512];

    const int tx = threadIdx.x, ty = threadIdx.y;
    const int tid = tx + (ty << 3);
    const int X0 = blockIdx.x * 64, Y0 = blockIdx.y * 64;
    const int b = blockIdx.z;

    const float* __restrict__ in  = state_base + (size_t)(b * NSLICE + (t - 1)) * IMG;
    float* __restrict__ outp      = out_base   + (size_t)(b * NSLICE + t) * IMG;

    // weights -> LDS (broadcast reads later, conflict-free, in-order lgkm)
    for (int j = tid; j < 128; j += 256)
        *(float4*)&wlds[4 * j] = *(const float4*)&wsf[4 * j];

    // stage 84 x 22 quads, swizzled
    for (int j = tid; j < IN_Y * NQ; j += 256) {
        int r = j / NQ, k = j - r * NQ;
        int gr = (Y0 + r - 10) & MASK;
        int gc = (X0 + 4 * k - 12) & MASK;
        *(float4*)&tile[lds_q(r, k)] = *(const float4*)&in[gr * HW + gc];
    }
    __syncthreads();

    const int tx2 = tx << 1;           // starting quad of this thread's window
    const int r0  = ty << 1;           // 2 adjacent output rows per thread

    float win[32], wA[24], wB[24];

    auto LOADWIN = [&](int rr) {
        int r = r0 + rr;
        int base = r * ROWW;
        int m = (r >> 1) & 7;
        #pragma unroll
        for (int k = 0; k < 8; ++k) {
            float4 q = *(const float4*)&tile[base + (((tx2 + k) ^ m) << 2)];
            win[4*k] = q.x; win[4*k+1] = q.y; win[4*k+2] = q.z; win[4*k+3] = q.w;
        }
    };
    auto LOADW = [&](float* w, int rr) {   // broadcast (same addr all lanes)
        #pragma unroll
        for (int k = 0; k < 6; ++k) {
            float4 q = *(const float4*)&wlds[rr * 24 + 4 * k];
            w[4*k] = q.x; w[4*k+1] = q.y; w[4*k+2] = q.z; w[4*k+3] = q.w;
        }
    };
    auto CONV = [&](float* acc, const float* w) {
        #pragma unroll
        for (int dx = 0; dx < 21; ++dx)
            #pragma unroll
            for (int cc = 0; cc < 8; ++cc)
                acc[cc] = fmaf(w[dx], win[cc + dx + 2], acc[cc]);
    };

    float acc0[8], acc1[8];
    #pragma unroll
    for (int cc = 0; cc < 8; ++cc) { acc0[cc] = 0.f; acc1[cc] = 0.f; }

    // staged row r0+rr feeds out0 with weight row rr, out1 with rr-1
    LOADW(wA, 0); LOADWIN(0); CONV(acc0, wA);
    LOADW(wB, 1); LOADWIN(1); CONV(acc0, wB); CONV(acc1, wA);
    #pragma unroll 1
    for (int i = 1; i <= 9; ++i) {     // invariant: wB = weight row 2i-1
        LOADW(wA, 2*i);   LOADWIN(2*i);   CONV(acc0, wA); CONV(acc1, wB);
        LOADW(wB, 2*i+1); LOADWIN(2*i+1); CONV(acc0, wB); CONV(acc1, wA);
    }
    LOADW(wA, 20); LOADWIN(20); CONV(acc0, wA); CONV(acc1, wB);
    LOADWIN(21); CONV(acc1, wA);

    const float C = wlds[504];

    // centers (residual x): rows r0+10 / r0+11 share mask m = (ty+5)&7
    {
        int rA = r0 + 10, rB = r0 + 11;
        int m = (rA >> 1) & 7;
        float4 u0 = *(const float4*)&tile[rA * ROWW + (((tx2 + 3) ^ m) << 2)];
        float4 u1 = *(const float4*)&tile[rA * ROWW + (((tx2 + 4) ^ m) << 2)];
        float4 v0 = *(const float4*)&tile[rB * ROWW + (((tx2 + 3) ^ m) << 2)];
        float4 v1 = *(const float4*)&tile[rB * ROWW + (((tx2 + 4) ^ m) << 2)];
        float ctr0[8] = {u0.x,u0.y,u0.z,u0.w,u1.x,u1.y,u1.z,u1.w};
        float ctr1[8] = {v0.x,v0.y,v0.z,v0.w,v1.x,v1.y,v1.z,v1.w};
        float o0[8], o1[8];
        #pragma unroll
        for (int cc = 0; cc < 8; ++cc) {
            float a  = ctr0[cc] + C * fmaxf(acc0[cc], 0.f);
            float e  = __expf(2.f * fabsf(a));                 // tanh via exp
            float rr = 1.f - 2.f * __builtin_amdgcn_rcpf(e + 1.f);
            o0[cc]   = copysignf(rr, a);
            float a1 = ctr1[cc] + C * fmaxf(acc1[cc], 0.f);
            float e1 = __expf(2.f * fabsf(a1));
            float r1 = 1.f - 2.f * __builtin_amdgcn_rcpf(e1 + 1.f);
            o1[cc]   = copysignf(r1, a1);
        }
        float4* po0 = (float4*)&outp[(size_t)(Y0 + r0) * HW + X0 + (tx << 3)];
        po0[0] = make_float4(o0[0], o0[1], o0[2], o0[3]);
        po0[1] = make_float4(o0[4], o0[5], o0[6], o0[7]);
        float4* po1 = (float4*)&outp[(size_t)(Y0 + r0 + 1) * HW + X0 + (tx << 3)];
        po1[0] = make_float4(o1[0], o1[1], o1[2], o1[3]);
        po1[1] = make_float4(o1[4], o1[5], o1[6], o1[7]);
    }
}

extern "C" void kernel_launch(void* const* d_in, const int* in_sizes, int n_in,
                              void* d_out, int out_size, void* d_ws, size_t ws_size,
                              hipStream_t stream) {
    const float* x  = (const float*)d_in[0];
    const float* w1 = (const float*)d_in[1];
    const float* w2 = (const float*)d_in[2];
    const float* w3 = (const float*)d_in[3];
    float* out = (float*)d_out;
    float* ws  = (float*)d_ws;

    prep_kernel<<<1, 128, 0, stream>>>(w1, w2, w3, ws);
    copy_kernel<<<2048, 256, 0, stream>>>(x, out);

    dim3 grid(8, 8, 8);      // 512 blocks = 2/CU
    dim3 block(8, 32);
    for (int t = 1; t <= NSTEP; ++t)
        step_kernel<<<grid, block, 0, stream>>>(out, out, ws, t);
}